// Round 1
// baseline (298.701 us; speedup 1.0000x reference)
//
#include <hip/hip_runtime.h>
#include <math.h>

// Problem constants (from reference): B=4096 rows, N=2048 elements/row, fp32.
constexpr int N_ELEM = 2048;
constexpr int BATCH  = 4096;
constexpr int BLOCK  = 256;

// One block per (pair, batch row). Reads o[b,:], t[b,:] (8 KiB each),
// computes ssd / max(t) / min(t), and atomically accumulates
// w * sqrt(ssd/N) / (max-min) / B into *out.
__global__ __launch_bounds__(BLOCK)
void wnrmse_kernel(const float* __restrict__ o1, const float* __restrict__ t1,
                   const float* __restrict__ o2, const float* __restrict__ t2,
                   const float* __restrict__ o3, const float* __restrict__ t3,
                   float* __restrict__ out)
{
    const int b    = blockIdx.x;      // batch row
    const int pair = blockIdx.y;      // 0,1,2

    const float* o;
    const float* t;
    float w;
    if (pair == 0)      { o = o1; t = t1; w = 0.50f; }
    else if (pair == 1) { o = o2; t = t2; w = 0.25f; }
    else                { o = o3; t = t3; w = 0.25f; }

    const float4* o4 = (const float4*)(o + (size_t)b * N_ELEM);
    const float4* t4 = (const float4*)(t + (size_t)b * N_ELEM);

    const int tid = threadIdx.x;

    float ssd  = 0.0f;
    float tmax = -INFINITY;
    float tmin =  INFINITY;

    // N/4 = 512 float4 per row; 256 threads -> 2 iterations, coalesced.
#pragma unroll
    for (int it = 0; it < (N_ELEM / 4) / BLOCK; ++it) {
        const int i = tid + it * BLOCK;
        float4 ov = o4[i];
        float4 tv = t4[i];
        float d0 = ov.x - tv.x;
        float d1 = ov.y - tv.y;
        float d2 = ov.z - tv.z;
        float d3 = ov.w - tv.w;
        ssd += d0 * d0 + d1 * d1 + d2 * d2 + d3 * d3;
        tmax = fmaxf(tmax, fmaxf(fmaxf(tv.x, tv.y), fmaxf(tv.z, tv.w)));
        tmin = fminf(tmin, fminf(fminf(tv.x, tv.y), fminf(tv.z, tv.w)));
    }

    // Wave-64 butterfly reduce.
#pragma unroll
    for (int off = 32; off > 0; off >>= 1) {
        ssd  += __shfl_xor(ssd, off, 64);
        tmax  = fmaxf(tmax, __shfl_xor(tmax, off, 64));
        tmin  = fminf(tmin, __shfl_xor(tmin, off, 64));
    }

    // Cross-wave reduce (4 waves/block) via LDS.
    __shared__ float s_ssd[4], s_max[4], s_min[4];
    const int wave = tid >> 6;
    const int lane = tid & 63;
    if (lane == 0) {
        s_ssd[wave] = ssd;
        s_max[wave] = tmax;
        s_min[wave] = tmin;
    }
    __syncthreads();

    if (tid == 0) {
        float S = s_ssd[0] + s_ssd[1] + s_ssd[2] + s_ssd[3];
        float M = fmaxf(fmaxf(s_max[0], s_max[1]), fmaxf(s_max[2], s_max[3]));
        float m = fminf(fminf(s_min[0], s_min[1]), fminf(s_min[2], s_min[3]));
        float rmse = sqrtf(S * (1.0f / (float)N_ELEM));
        float val  = w * rmse / (M - m) * (1.0f / (float)BATCH);
        atomicAdd(out, val);   // device-scope by default on CDNA
    }
}

extern "C" void kernel_launch(void* const* d_in, const int* in_sizes, int n_in,
                              void* d_out, int out_size, void* d_ws, size_t ws_size,
                              hipStream_t stream) {
    const float* o1 = (const float*)d_in[0];
    const float* t1 = (const float*)d_in[1];
    const float* o2 = (const float*)d_in[2];
    const float* t2 = (const float*)d_in[3];
    const float* o3 = (const float*)d_in[4];
    const float* t3 = (const float*)d_in[5];
    float* out = (float*)d_out;

    // d_out is re-poisoned to 0xAA before every timed launch -> zero it.
    hipMemsetAsync(out, 0, sizeof(float), stream);

    dim3 grid(BATCH, 3, 1);
    dim3 block(BLOCK, 1, 1);
    wnrmse_kernel<<<grid, block, 0, stream>>>(o1, t1, o2, t2, o3, t3, out);
}

// Round 2
// 203.262 us; speedup vs baseline: 1.4695x; 1.4695x over previous
//
#include <hip/hip_runtime.h>
#include <math.h>

// Problem: loss = mean_b[ 0.5*nrmse(o1,t1) + 0.25*nrmse(o2,t2) + 0.25*nrmse(o3,t3) ]
// B=4096 rows, N=2048 fp32 per row. Purely memory-bound (192 MiB in, 4 B out).
constexpr int N_ELEM = 2048;
constexpr int BATCH  = 4096;
constexpr int BLOCK  = 256;              // 4 waves/block
constexpr int GRID1  = 1536;             // 6 blocks/CU on 256 CUs, one dispatch round
constexpr int WAVES1 = GRID1 * (BLOCK / 64);   // 6144 waves
constexpr int TASKS  = 3 * BATCH;              // 12288 (pair,row) tasks

// Stage 1: one wave per row. 64 lanes x 8 float4 per array -> 16 independent
// 16B loads in flight per lane; single wave shuffle-reduce per row; NO
// __syncthreads in the hot loop, NO atomics (partials to d_ws).
__global__ __launch_bounds__(BLOCK)
void wnrmse_stage1(const float* __restrict__ o1, const float* __restrict__ t1,
                   const float* __restrict__ o2, const float* __restrict__ t2,
                   const float* __restrict__ o3, const float* __restrict__ t3,
                   float* __restrict__ partial)
{
    const int tid  = threadIdx.x;
    const int wave = tid >> 6;
    const int lane = tid & 63;
    const int gw   = blockIdx.x * (BLOCK / 64) + wave;   // global wave id

    const float* const os[3] = { o1, o2, o3 };
    const float* const ts[3] = { t1, t2, t3 };
    const float wgt[3] = { 0.50f, 0.25f, 0.25f };

    float local = 0.0f;   // sum of w * rmse / range over this wave's rows

    for (int task = gw; task < TASKS; task += WAVES1) {   // 2 iterations
        const int pair = task >> 12;          // task / 4096
        const int row  = task & (BATCH - 1);  // task % 4096

        const float4* o4 = (const float4*)(os[pair] + (size_t)row * N_ELEM);
        const float4* t4 = (const float4*)(ts[pair] + (size_t)row * N_ELEM);

        float ssd  = 0.0f;
        float tmax = -INFINITY;
        float tmin =  INFINITY;

        // 512 float4 per row / 64 lanes = 8 per lane, coalesced.
#pragma unroll
        for (int j = 0; j < (N_ELEM / 4) / 64; ++j) {
            const int i = lane + j * 64;
            float4 ov = o4[i];
            float4 tv = t4[i];
            float d0 = ov.x - tv.x;
            float d1 = ov.y - tv.y;
            float d2 = ov.z - tv.z;
            float d3 = ov.w - tv.w;
            ssd += d0 * d0 + d1 * d1 + d2 * d2 + d3 * d3;
            tmax = fmaxf(tmax, fmaxf(fmaxf(tv.x, tv.y), fmaxf(tv.z, tv.w)));
            tmin = fminf(tmin, fminf(fminf(tv.x, tv.y), fminf(tv.z, tv.w)));
        }

        // Wave-64 butterfly reduce; all lanes end with the row result.
#pragma unroll
        for (int off = 32; off > 0; off >>= 1) {
            ssd  += __shfl_xor(ssd, off, 64);
            tmax  = fmaxf(tmax, __shfl_xor(tmax, off, 64));
            tmin  = fminf(tmin, __shfl_xor(tmin, off, 64));
        }

        float rmse = sqrtf(ssd * (1.0f / (float)N_ELEM));
        local += wgt[pair] * rmse / (tmax - tmin);
    }

    // Per-block combine (once per kernel, not per row), then one plain store.
    __shared__ float s_part[BLOCK / 64];
    if (lane == 0) s_part[wave] = local;
    __syncthreads();
    if (tid == 0) {
        partial[blockIdx.x] = s_part[0] + s_part[1] + s_part[2] + s_part[3];
    }
}

// Stage 2: one block reduces GRID1 partials and writes the final scalar.
__global__ __launch_bounds__(BLOCK)
void wnrmse_stage2(const float* __restrict__ partial, float* __restrict__ out)
{
    const int tid = threadIdx.x;
    float s = 0.0f;
    for (int i = tid; i < GRID1; i += BLOCK) s += partial[i];

#pragma unroll
    for (int off = 32; off > 0; off >>= 1) s += __shfl_xor(s, off, 64);

    __shared__ float s_part[BLOCK / 64];
    const int wave = tid >> 6;
    const int lane = tid & 63;
    if (lane == 0) s_part[wave] = s;
    __syncthreads();
    if (tid == 0) {
        float tot = s_part[0] + s_part[1] + s_part[2] + s_part[3];
        out[0] = tot * (1.0f / (float)BATCH);
    }
}

extern "C" void kernel_launch(void* const* d_in, const int* in_sizes, int n_in,
                              void* d_out, int out_size, void* d_ws, size_t ws_size,
                              hipStream_t stream) {
    const float* o1 = (const float*)d_in[0];
    const float* t1 = (const float*)d_in[1];
    const float* o2 = (const float*)d_in[2];
    const float* t2 = (const float*)d_in[3];
    const float* o3 = (const float*)d_in[4];
    const float* t3 = (const float*)d_in[5];
    float* out     = (float*)d_out;
    float* partial = (float*)d_ws;    // GRID1 floats = 6 KiB, fully overwritten

    wnrmse_stage1<<<GRID1, BLOCK, 0, stream>>>(o1, t1, o2, t2, o3, t3, partial);
    wnrmse_stage2<<<1, BLOCK, 0, stream>>>(partial, out);
}